// Round 1
// baseline (1784.442 us; speedup 1.0000x reference)
//
#include <hip/hip_runtime.h>
#include <math.h>

#define B_  128
#define C_  512
#define S_  128
#define M_  512
#define BN_EPS 1e-5f

// ---------------------------------------------------------------------------
// Tiled fp32 GEMM:  C[i,j] = scale * sum_k A[i,k] * Bop[k,j]  (+ bias[j])
//   A is [M,K] row-major.
//   transB=1: Bop[k,j] = Bm[j*K + k]   (Bm is [N,K] row-major)  -- "NT"
//   transB=0: Bop[k,j] = Bm[k*N + j]   (Bm is [K,N] row-major)  -- "NN"
// Batched over blockIdx.z with element strides sA/sB/sC (0 = shared operand).
// 64x64 block tile, 16 K-tile, 256 threads, 4x4 per thread.
// All problem dims here divide the tile sizes exactly -> no bounds checks.
// ---------------------------------------------------------------------------
__global__ __launch_bounds__(256)
void gemm_kernel(const float* __restrict__ A, const float* __restrict__ Bm,
                 const float* __restrict__ bias, float* __restrict__ Cc,
                 int M, int N, int K,
                 long sA, long sB, long sC, float scale, int transB)
{
    const int bz = blockIdx.z;
    A  += (long)bz * sA;
    Bm += (long)bz * sB;
    Cc += (long)bz * sC;

    __shared__ float As[16][64 + 1];
    __shared__ float Bs[16][64 + 1];

    const int t  = threadIdx.x;
    const int tx = t & 15;        // 0..15 (cols)
    const int ty = t >> 4;        // 0..15 (rows)
    const int row0 = blockIdx.x * 64;
    const int col0 = blockIdx.y * 64;

    float acc[4][4] = {};

    for (int k0 = 0; k0 < K; k0 += 16) {
        // ---- load A tile: 64 rows x 16 k, thread -> (row = t/4, 4 consecutive k)
        {
            const int arow = t >> 2;
            const int kq   = (t & 3) * 4;
            const float4 av = *(const float4*)(A + (long)(row0 + arow) * K + k0 + kq);
            As[kq + 0][arow] = av.x;
            As[kq + 1][arow] = av.y;
            As[kq + 2][arow] = av.z;
            As[kq + 3][arow] = av.w;
        }
        // ---- load B tile into Bs[k][col]
        if (transB) {
            const int bcol = t >> 2;
            const int kq   = (t & 3) * 4;
            const float4 bv = *(const float4*)(Bm + (long)(col0 + bcol) * K + k0 + kq);
            Bs[kq + 0][bcol] = bv.x;
            Bs[kq + 1][bcol] = bv.y;
            Bs[kq + 2][bcol] = bv.z;
            Bs[kq + 3][bcol] = bv.w;
        } else {
            const int kk = t >> 4;          // 0..15
            const int c4 = (t & 15) * 4;    // 0..60
            const float4 bv = *(const float4*)(Bm + (long)(k0 + kk) * N + col0 + c4);
            Bs[kk][c4 + 0] = bv.x;
            Bs[kk][c4 + 1] = bv.y;
            Bs[kk][c4 + 2] = bv.z;
            Bs[kk][c4 + 3] = bv.w;
        }
        __syncthreads();

        #pragma unroll
        for (int kk = 0; kk < 16; ++kk) {
            float a[4], b[4];
            #pragma unroll
            for (int i = 0; i < 4; ++i) a[i] = As[kk][ty * 4 + i];
            #pragma unroll
            for (int j = 0; j < 4; ++j) b[j] = Bs[kk][tx * 4 + j];
            #pragma unroll
            for (int i = 0; i < 4; ++i)
                #pragma unroll
                for (int j = 0; j < 4; ++j)
                    acc[i][j] = fmaf(a[i], b[j], acc[i][j]);
        }
        __syncthreads();
    }

    // ---- epilogue
    #pragma unroll
    for (int i = 0; i < 4; ++i) {
        const int r = row0 + ty * 4 + i;
        #pragma unroll
        for (int j = 0; j < 4; ++j) {
            const int c = col0 + tx * 4 + j;
            float v = acc[i][j] * scale;
            if (bias) v += bias[c];
            Cc[(long)r * N + c] = v;
        }
    }
}

// ---------------------------------------------------------------------------
// Row softmax over 512 cols, in place. One 64-lane wave per row, 4 rows/block.
// ---------------------------------------------------------------------------
__global__ __launch_bounds__(256)
void softmax_kernel(float* __restrict__ attn)
{
    const int row  = blockIdx.x * 4 + (threadIdx.x >> 6);
    const int lane = threadIdx.x & 63;
    float4* p = (float4*)(attn + (long)row * 512);

    float4 a = p[lane];
    float4 b = p[lane + 64];

    float mx = fmaxf(fmaxf(fmaxf(a.x, a.y), fmaxf(a.z, a.w)),
                     fmaxf(fmaxf(b.x, b.y), fmaxf(b.z, b.w)));
    #pragma unroll
    for (int off = 1; off < 64; off <<= 1)
        mx = fmaxf(mx, __shfl_xor(mx, off));

    a.x = expf(a.x - mx); a.y = expf(a.y - mx);
    a.z = expf(a.z - mx); a.w = expf(a.w - mx);
    b.x = expf(b.x - mx); b.y = expf(b.y - mx);
    b.z = expf(b.z - mx); b.w = expf(b.w - mx);

    float sum = a.x + a.y + a.z + a.w + b.x + b.y + b.z + b.w;
    #pragma unroll
    for (int off = 1; off < 64; off <<= 1)
        sum += __shfl_xor(sum, off);

    const float inv = 1.0f / sum;
    a.x *= inv; a.y *= inv; a.z *= inv; a.w *= inv;
    b.x *= inv; b.y *= inv; b.z *= inv; b.w *= inv;

    p[lane]      = a;
    p[lane + 64] = b;
}

// ---------------------------------------------------------------------------
// BatchNorm stats: one block per channel c, reduce over (b, s) = 128*128.
// stats[c] = mean, stats[C_+c] = rsqrt(var + eps)
// ---------------------------------------------------------------------------
__global__ __launch_bounds__(256)
void bn_stats_kernel(const float* __restrict__ outp, float* __restrict__ stats)
{
    const int c   = blockIdx.x;
    const int tid = threadIdx.x;
    float s = 0.f, ss = 0.f;
    for (int idx = tid; idx < B_ * S_; idx += 256) {
        const int b  = idx >> 7;    // / S_
        const int sp = idx & 127;   // % S_
        const float x = outp[((long)b * C_ + c) * S_ + sp];
        s  += x;
        ss += x * x;
    }
    __shared__ float shs[256];
    __shared__ float shss[256];
    shs[tid] = s; shss[tid] = ss;
    __syncthreads();
    for (int off = 128; off > 0; off >>= 1) {
        if (tid < off) { shs[tid] += shs[tid + off]; shss[tid] += shss[tid + off]; }
        __syncthreads();
    }
    if (tid == 0) {
        const float n    = (float)(B_ * S_);
        const float mean = shs[0] / n;
        const float var  = shss[0] / n - mean * mean;
        stats[c]      = mean;
        stats[C_ + c] = rsqrtf(var + BN_EPS);
    }
}

// ---------------------------------------------------------------------------
// Apply BN + ReLU + residual:  out = value + relu((x-mean)*istd*gamma + beta)
// float4 elementwise, c constant within a float4 (S_ % 4 == 0).
// ---------------------------------------------------------------------------
__global__ __launch_bounds__(256)
void bn_apply_kernel(const float* __restrict__ outp, const float* __restrict__ value,
                     const float* __restrict__ stats, const float* __restrict__ gamma,
                     const float* __restrict__ beta, float* __restrict__ out)
{
    const long i4 = (long)blockIdx.x * 256 + threadIdx.x;   // float4 index
    const int  c  = (int)((i4 >> 5) & (C_ - 1));            // ((i4*4)/S_) % C_

    const float mean = stats[c];
    const float istd = stats[C_ + c];
    const float g    = gamma[c] * istd;
    const float bc   = beta[c] - mean * g;

    const float4 x = ((const float4*)outp)[i4];
    const float4 r = ((const float4*)value)[i4];
    float4 y;
    y.x = fmaxf(fmaf(x.x, g, bc), 0.f) + r.x;
    y.y = fmaxf(fmaf(x.y, g, bc), 0.f) + r.y;
    y.z = fmaxf(fmaf(x.z, g, bc), 0.f) + r.z;
    y.w = fmaxf(fmaf(x.w, g, bc), 0.f) + r.w;
    ((float4*)out)[i4] = y;
}

// ---------------------------------------------------------------------------
extern "C" void kernel_launch(void* const* d_in, const int* in_sizes, int n_in,
                              void* d_out, int out_size, void* d_ws, size_t ws_size,
                              hipStream_t stream)
{
    const float* query = (const float*)d_in[0];
    const float* key   = (const float*)d_in[1];
    const float* value = (const float*)d_in[2];
    const float* Wq    = (const float*)d_in[3];
    const float* bq    = (const float*)d_in[4];
    const float* Wk    = (const float*)d_in[5];
    const float* bk    = (const float*)d_in[6];
    const float* Wv    = (const float*)d_in[7];
    const float* bv    = (const float*)d_in[8];
    const float* Wf    = (const float*)d_in[9];
    const float* bf    = (const float*)d_in[10];
    const float* gamma = (const float*)d_in[11];
    const float* beta  = (const float*)d_in[12];

    const long BC  = (long)B_ * C_;         // 65536
    const long BCM = BC * M_;               // 33,554,432 elements
    const long BCS = BC * S_;               //  8,388,608 elements

    float* ws   = (float*)d_ws;
    float* q    = ws;                       // [B*C, M]
    float* k    = ws + BCM;                 // [B*C, M]
    float* v2   = ws + 2 * BCM;             // [B*C, M]
    // q region is dead after scores -> reuse for vw and out_pre
    float* vw   = ws;                       // [B*C, S]  (v2 @ Wf^T + bf)
    float* outp = ws + BCS;                 // [B*C, S]  (pre-BN out)
    // k region is dead after scores -> reuse for stats
    float* stats = ws + BCM;                // [2*C]

    float* out0 = (float*)d_out;            // [B, C, S]
    float* attn = out0 + BCS;               // [B, C, C] (output 1)

    const float scale = 1.0f / sqrtf((float)M_);
    dim3 blk(256);

    // 1. projections: [B*C,S] x [M,S]^T -> [B*C,M]
    gemm_kernel<<<dim3(BC / 64, M_ / 64, 1), blk, 0, stream>>>(
        query, Wq, bq, q,  (int)BC, M_, S_, 0, 0, 0, 1.0f, 1);
    gemm_kernel<<<dim3(BC / 64, M_ / 64, 1), blk, 0, stream>>>(
        key,   Wk, bk, k,  (int)BC, M_, S_, 0, 0, 0, 1.0f, 1);
    gemm_kernel<<<dim3(BC / 64, M_ / 64, 1), blk, 0, stream>>>(
        value, Wv, bv, v2, (int)BC, M_, S_, 0, 0, 0, 1.0f, 1);

    // 2. scores = scale * q @ k^T  (batched over B) -> attn (raw)
    gemm_kernel<<<dim3(C_ / 64, C_ / 64, B_), blk, 0, stream>>>(
        q, k, nullptr, attn, C_, C_, M_,
        (long)C_ * M_, (long)C_ * M_, (long)C_ * C_, scale, 1);

    // 3. softmax rows in place -> attention (output 1 done)
    softmax_kernel<<<dim3(BC / 4), blk, 0, stream>>>(attn);

    // 4. vw = v2 @ Wf^T + bf : [B*C,M] x [S,M]^T -> [B*C,S]
    //    (bias folded in is exact because softmax rows sum to 1)
    gemm_kernel<<<dim3(BC / 64, S_ / 64, 1), blk, 0, stream>>>(
        v2, Wf, bf, vw, (int)BC, S_, M_, 0, 0, 0, 1.0f, 1);

    // 5. out_pre = attn @ vw  (batched NN): [C,C] x [C,S] -> [C,S]
    gemm_kernel<<<dim3(C_ / 64, S_ / 64, B_), blk, 0, stream>>>(
        attn, vw, nullptr, outp, C_, S_, C_,
        (long)C_ * C_, (long)C_ * S_, (long)C_ * S_, 1.0f, 0);

    // 6. BN stats per channel
    bn_stats_kernel<<<dim3(C_), blk, 0, stream>>>(outp, stats);

    // 7. BN apply + ReLU + residual -> out (output 0 done)
    bn_apply_kernel<<<dim3(BCS / 4 / 256), blk, 0, stream>>>(
        outp, value, stats, gamma, beta, out0);
}

// Round 2
// 649.025 us; speedup vs baseline: 2.7494x; 2.7494x over previous
//
#include <hip/hip_runtime.h>
#include <math.h>

#define B_  128
#define C_  512
#define S_  128
#define M_  512
#define BN_EPS 1e-5f

typedef __attribute__((ext_vector_type(8))) short   short8;
typedef __attribute__((ext_vector_type(4))) float   floatx4;
typedef __attribute__((ext_vector_type(4))) unsigned short ushort4v;

// fp32 -> bf16 bits, round-to-nearest-even (finite inputs)
__device__ __forceinline__ unsigned short f2bu(float f) {
    union { float f; unsigned int u; } c; c.f = f;
    unsigned int u = c.u;
    return (unsigned short)((u + 0x7fffu + ((u >> 16) & 1u)) >> 16);
}

// ---------------------------------------------------------------------------
// fp32 -> bf16 conversion, 8 elems/thread
// ---------------------------------------------------------------------------
__global__ __launch_bounds__(256)
void f2bf_kernel(const float* __restrict__ in, unsigned short* __restrict__ out, long n8)
{
    const long i = (long)blockIdx.x * 256 + threadIdx.x;
    if (i >= n8) return;
    const float4* p = (const float4*)in + 2 * i;
    const float4 x = p[0], y = p[1];
    ushort4v u0, u1;
    u0.x = f2bu(x.x); u0.y = f2bu(x.y); u0.z = f2bu(x.z); u0.w = f2bu(x.w);
    u1.x = f2bu(y.x); u1.y = f2bu(y.y); u1.z = f2bu(y.z); u1.w = f2bu(y.w);
    ((ushort4v*)out)[2 * i]     = u0;
    ((ushort4v*)out)[2 * i + 1] = u1;
}

// ---------------------------------------------------------------------------
// bf16 MFMA GEMM, NT form: C[i,j] = scale * sum_k A[i,k]*Bm[j,k] (+ bias[j])
//   A: [M,K] bf16 row-major (ldA), Bm: [N,K] bf16 row-major (ldB)
//   Batched over blockIdx.z with element strides sA/sB/sC.
//   outMode 0: fp32 C [ldC];  1: bf16 C [ldC];
//           2: bf16 scattered vwT: addr = (r>>9)*65536 + col*512 + (r&511)
// Tile: BM=BN=128, BK=64. 256 thr = 4 waves (2x2), each wave 64x64 via
// 4x4 grid of 16x16x32 MFMA. LDS rows padded to 72 bf16.
// All dims divide tiles exactly -> no bounds checks.
// ---------------------------------------------------------------------------
__global__ __launch_bounds__(256)
void gemm_bf16(const unsigned short* __restrict__ A, const unsigned short* __restrict__ Bm,
               const float* __restrict__ bias, void* __restrict__ Cc,
               int M, int N, int K, int ldA, int ldB, int ldC,
               long sA, long sB, long sC, float scale, int outMode)
{
    const int bz = blockIdx.z;
    A  += (long)bz * sA;
    Bm += (long)bz * sB;

    __shared__ unsigned short As[128][72];
    __shared__ unsigned short Bs[128][72];

    const int t    = threadIdx.x;
    const int lane = t & 63;
    const int wave = t >> 6;          // 0..3
    const int wm   = (wave >> 1) * 64;
    const int wn   = (wave & 1) * 64;
    const int lrow = lane & 15;
    const int quad = lane >> 4;
    const int row0 = blockIdx.x * 128;
    const int col0 = blockIdx.y * 128;

    floatx4 acc[4][4] = {};

    const int srow = t >> 3;          // staging base row 0..31 step (+32/iter)
    const int skc  = (t & 7) * 8;     // staging k offset

    for (int k0 = 0; k0 < K; k0 += 64) {
        // ---- stage A and B tiles (4 chunks each per thread)
        #pragma unroll
        for (int i = 0; i < 4; ++i) {
            const int r = srow + i * 32;
            *(short8*)&As[r][skc] =
                *(const short8*)(A + (long)(row0 + r) * ldA + k0 + skc);
            *(short8*)&Bs[r][skc] =
                *(const short8*)(Bm + (long)(col0 + r) * ldB + k0 + skc);
        }
        __syncthreads();

        // ---- 2 k-steps of 32
        #pragma unroll
        for (int kb = 0; kb < 2; ++kb) {
            short8 af[4], bfr[4];
            #pragma unroll
            for (int i = 0; i < 4; ++i)
                af[i]  = *(const short8*)&As[wm + i * 16 + lrow][kb * 32 + quad * 8];
            #pragma unroll
            for (int j = 0; j < 4; ++j)
                bfr[j] = *(const short8*)&Bs[wn + j * 16 + lrow][kb * 32 + quad * 8];
            #pragma unroll
            for (int i = 0; i < 4; ++i)
                #pragma unroll
                for (int j = 0; j < 4; ++j)
                    acc[i][j] = __builtin_amdgcn_mfma_f32_16x16x32_bf16(
                        af[i], bfr[j], acc[i][j], 0, 0, 0);
        }
        __syncthreads();
    }

    // ---- epilogue. C/D layout: col=lane&15, row=(lane>>4)*4+reg
    #pragma unroll
    for (int j = 0; j < 4; ++j) {
        const int col = col0 + wn + j * 16 + lrow;
        const float bv = bias ? bias[col] : 0.0f;
        #pragma unroll
        for (int i = 0; i < 4; ++i) {
            const int rbase = row0 + wm + i * 16 + quad * 4;
            #pragma unroll
            for (int reg = 0; reg < 4; ++reg) {
                const float val = acc[i][j][reg] * scale + bv;
                const int r = rbase + reg;
                if (outMode == 0) {
                    ((float*)Cc)[(long)bz * sC + (long)r * ldC + col] = val;
                } else if (outMode == 1) {
                    ((unsigned short*)Cc)[(long)bz * sC + (long)r * ldC + col] = f2bu(val);
                } else {
                    ((unsigned short*)Cc)[((long)(r >> 9)) * 65536 + (long)col * 512 + (r & 511)] = f2bu(val);
                }
            }
        }
    }
}

// ---------------------------------------------------------------------------
// Row softmax over 512 cols, fp32 in place + bf16 copy.
// One 64-lane wave per row, 4 rows/block.
// ---------------------------------------------------------------------------
__global__ __launch_bounds__(256)
void softmax_kernel(float* __restrict__ attn, unsigned short* __restrict__ attn_bf)
{
    const int row  = blockIdx.x * 4 + (threadIdx.x >> 6);
    const int lane = threadIdx.x & 63;
    float4* p = (float4*)(attn + (long)row * 512);

    float4 a = p[lane];
    float4 b = p[lane + 64];

    float mx = fmaxf(fmaxf(fmaxf(a.x, a.y), fmaxf(a.z, a.w)),
                     fmaxf(fmaxf(b.x, b.y), fmaxf(b.z, b.w)));
    #pragma unroll
    for (int off = 1; off < 64; off <<= 1)
        mx = fmaxf(mx, __shfl_xor(mx, off));

    a.x = expf(a.x - mx); a.y = expf(a.y - mx);
    a.z = expf(a.z - mx); a.w = expf(a.w - mx);
    b.x = expf(b.x - mx); b.y = expf(b.y - mx);
    b.z = expf(b.z - mx); b.w = expf(b.w - mx);

    float sum = a.x + a.y + a.z + a.w + b.x + b.y + b.z + b.w;
    #pragma unroll
    for (int off = 1; off < 64; off <<= 1)
        sum += __shfl_xor(sum, off);

    const float inv = 1.0f / sum;
    a.x *= inv; a.y *= inv; a.z *= inv; a.w *= inv;
    b.x *= inv; b.y *= inv; b.z *= inv; b.w *= inv;

    p[lane]      = a;
    p[lane + 64] = b;

    ushort4v u0, u1;
    u0.x = f2bu(a.x); u0.y = f2bu(a.y); u0.z = f2bu(a.z); u0.w = f2bu(a.w);
    u1.x = f2bu(b.x); u1.y = f2bu(b.y); u1.z = f2bu(b.z); u1.w = f2bu(b.w);
    ushort4v* q = (ushort4v*)(attn_bf + (long)row * 512);
    q[lane]      = u0;
    q[lane + 64] = u1;
}

// ---------------------------------------------------------------------------
// BatchNorm stats: one block per channel c, reduce over (b, s).
// ---------------------------------------------------------------------------
__global__ __launch_bounds__(256)
void bn_stats_kernel(const float* __restrict__ outp, float* __restrict__ stats)
{
    const int c   = blockIdx.x;
    const int tid = threadIdx.x;
    float s = 0.f, ss = 0.f;
    for (int idx = tid; idx < B_ * S_; idx += 256) {
        const int b  = idx >> 7;
        const int sp = idx & 127;
        const float x = outp[((long)b * C_ + c) * S_ + sp];
        s  += x;
        ss += x * x;
    }
    __shared__ float shs[256];
    __shared__ float shss[256];
    shs[tid] = s; shss[tid] = ss;
    __syncthreads();
    for (int off = 128; off > 0; off >>= 1) {
        if (tid < off) { shs[tid] += shs[tid + off]; shss[tid] += shss[tid + off]; }
        __syncthreads();
    }
    if (tid == 0) {
        const float n    = (float)(B_ * S_);
        const float mean = shs[0] / n;
        const float var  = shss[0] / n - mean * mean;
        stats[c]      = mean;
        stats[C_ + c] = rsqrtf(var + BN_EPS);
    }
}

// ---------------------------------------------------------------------------
// BN + ReLU + residual
// ---------------------------------------------------------------------------
__global__ __launch_bounds__(256)
void bn_apply_kernel(const float* __restrict__ outp, const float* __restrict__ value,
                     const float* __restrict__ stats, const float* __restrict__ gamma,
                     const float* __restrict__ beta, float* __restrict__ out)
{
    const long i4 = (long)blockIdx.x * 256 + threadIdx.x;
    const int  c  = (int)((i4 >> 5) & (C_ - 1));

    const float mean = stats[c];
    const float istd = stats[C_ + c];
    const float g    = gamma[c] * istd;
    const float bc   = beta[c] - mean * g;

    const float4 x = ((const float4*)outp)[i4];
    const float4 r = ((const float4*)value)[i4];
    float4 y;
    y.x = fmaxf(fmaf(x.x, g, bc), 0.f) + r.x;
    y.y = fmaxf(fmaf(x.y, g, bc), 0.f) + r.y;
    y.z = fmaxf(fmaf(x.z, g, bc), 0.f) + r.z;
    y.w = fmaxf(fmaf(x.w, g, bc), 0.f) + r.w;
    ((float4*)out)[i4] = y;
}

// ---------------------------------------------------------------------------
extern "C" void kernel_launch(void* const* d_in, const int* in_sizes, int n_in,
                              void* d_out, int out_size, void* d_ws, size_t ws_size,
                              hipStream_t stream)
{
    const float* query = (const float*)d_in[0];
    const float* key   = (const float*)d_in[1];
    const float* value = (const float*)d_in[2];
    const float* Wq    = (const float*)d_in[3];
    const float* bq    = (const float*)d_in[4];
    const float* Wk    = (const float*)d_in[5];
    const float* bk    = (const float*)d_in[6];
    const float* Wv    = (const float*)d_in[7];
    const float* bv    = (const float*)d_in[8];
    const float* Wf    = (const float*)d_in[9];
    const float* bf    = (const float*)d_in[10];
    const float* gamma = (const float*)d_in[11];
    const float* beta  = (const float*)d_in[12];

    const long BC  = (long)B_ * C_;       // 65536
    const long BCM = BC * M_;             // 33,554,432
    const long BCS = BC * S_;             //  8,388,608
    const long BCC = BC * C_;             // 33,554,432

    // ---- workspace carve (bf16 = ushort). All offsets 16B-aligned.
    unsigned short* w      = (unsigned short*)d_ws;
    unsigned short* q_bf   = w;                     // [BC, M]
    unsigned short* k_bf   = q_bf + BCM;            // [BC, M]
    unsigned short* v2_bf  = k_bf + BCM;            // [BC, M]
    unsigned short* attnbf = v2_bf + BCM;           // [B, C, C]
    unsigned short* vwT    = attnbf + BCC;          // [B, S, C]
    unsigned short* qin    = vwT + (long)B_ * S_ * C_;   // [BC, S]
    unsigned short* kin    = qin + BCS;
    unsigned short* vin    = kin + BCS;
    unsigned short* Wq_bf  = vin + BCS;             // [M, S]
    unsigned short* Wk_bf  = Wq_bf + (long)M_ * S_;
    unsigned short* Wv_bf  = Wk_bf + (long)M_ * S_;
    unsigned short* Wf_bf  = Wv_bf + (long)M_ * S_; // [S, M]
    float* outp  = (float*)(Wf_bf + (long)S_ * M_); // [BC, S] fp32
    float* stats = outp + BCS;                      // [2*C]

    float* out0 = (float*)d_out;          // [B, C, S]
    float* attn = out0 + BCS;             // [B, C, C]

    const float scale = 1.0f / sqrtf((float)M_);
    dim3 blk(256);

    // 0. fp32 -> bf16 conversions
    f2bf_kernel<<<dim3(BCS / 8 / 256), blk, 0, stream>>>(query, qin, BCS / 8);
    f2bf_kernel<<<dim3(BCS / 8 / 256), blk, 0, stream>>>(key,   kin, BCS / 8);
    f2bf_kernel<<<dim3(BCS / 8 / 256), blk, 0, stream>>>(value, vin, BCS / 8);
    f2bf_kernel<<<dim3(32), blk, 0, stream>>>(Wq, Wq_bf, (long)M_ * S_ / 8);
    f2bf_kernel<<<dim3(32), blk, 0, stream>>>(Wk, Wk_bf, (long)M_ * S_ / 8);
    f2bf_kernel<<<dim3(32), blk, 0, stream>>>(Wv, Wv_bf, (long)M_ * S_ / 8);
    f2bf_kernel<<<dim3(32), blk, 0, stream>>>(Wf, Wf_bf, (long)S_ * M_ / 8);

    // 1. projections: [BC,S] x [M,S]^T -> bf16 [BC,M]
    gemm_bf16<<<dim3(512, 4, 1), blk, 0, stream>>>(
        qin, Wq_bf, bq, q_bf,  (int)BC, M_, S_, S_, S_, M_, 0, 0, 0, 1.0f, 1);
    gemm_bf16<<<dim3(512, 4, 1), blk, 0, stream>>>(
        kin, Wk_bf, bk, k_bf,  (int)BC, M_, S_, S_, S_, M_, 0, 0, 0, 1.0f, 1);
    gemm_bf16<<<dim3(512, 4, 1), blk, 0, stream>>>(
        vin, Wv_bf, bv, v2_bf, (int)BC, M_, S_, S_, S_, M_, 0, 0, 0, 1.0f, 1);

    // 2. scores = scale * q @ k^T (batched) -> fp32 attn (d_out)
    gemm_bf16<<<dim3(4, 4, 128), blk, 0, stream>>>(
        q_bf, k_bf, nullptr, attn, C_, C_, M_, M_, M_, C_,
        (long)C_ * M_, (long)C_ * M_, (long)C_ * C_, scale, 0);

    // 3. softmax in place (output 1) + bf16 copy
    softmax_kernel<<<dim3(BC / 4), blk, 0, stream>>>(attn, attnbf);

    // 4. vw = v2 @ Wf^T + bf -> bf16, stored TRANSPOSED as vwT[b][s][c]
    //    (bias fold exact: softmax rows sum to 1)
    gemm_bf16<<<dim3(512, 1, 1), blk, 0, stream>>>(
        v2_bf, Wf_bf, bf, vwT, (int)BC, S_, M_, M_, M_, 0, 0, 0, 0, 1.0f, 2);

    // 5. outp = attn @ vw (NT via vwT): per batch [C,C] x [S,C]^T -> [C,S]
    gemm_bf16<<<dim3(4, 1, 128), blk, 0, stream>>>(
        attnbf, vwT, nullptr, outp, C_, S_, C_, C_, C_, S_,
        (long)C_ * C_, (long)S_ * C_, (long)C_ * S_, 1.0f, 0);

    // 6. BN stats
    bn_stats_kernel<<<dim3(C_), blk, 0, stream>>>(outp, stats);

    // 7. BN + ReLU + residual -> out0
    bn_apply_kernel<<<dim3(BCS / 4 / 256), blk, 0, stream>>>(
        outp, value, stats, gamma, beta, out0);
}